// Round 9
// baseline (206.885 us; speedup 1.0000x reference)
//
#include <hip/hip_runtime.h>

typedef unsigned int u32;
typedef unsigned short u16;
typedef float f4 __attribute__((ext_vector_type(4)));
typedef __bf16 b8 __attribute__((ext_vector_type(8)));
typedef unsigned short us8 __attribute__((ext_vector_type(8)));

#define DD 64
#define NE 16
#define OO 512
#define TR 64

struct __align__(16) Tile { u32 pid, slot, nr, pad; };

union U8 { us8 u; b8 b; };

__device__ __forceinline__ u16 f2bf(float f) {
  u32 u = __float_as_uint(f);
  u32 r = (u + 0x7fffu + ((u >> 16) & 1u)) >> 16;
  return (u16)r;
}

// ---------------- fused front: blocks [0,128) transpose We; blocks [128,384) gate ----------------
__global__ void k_front(const float* __restrict__ We, u16* __restrict__ WeT,
                        const float* __restrict__ x, const float* __restrict__ wg,
                        const float* __restrict__ bg, u32* __restrict__ hist_t,
                        u32* __restrict__ pid_arr, float* __restrict__ glo_arr,
                        float* __restrict__ ghi_arr, u32* __restrict__ cnt) {
  __shared__ float tl[64][65];     // wt path (16.6 KB)
  __shared__ u32 hcnt[256];        // gate path (1 KB)
  int t = threadIdx.x;

  if (blockIdx.x < 128) {
    if (blockIdx.x == 0 && t == 0) *cnt = 0u;   // reset k_meta's barrier counter (poisoned each iter)
    // ---- We [e][d][o] fp32 -> WeT [e][o][d] bf16 ----
    int b = blockIdx.x;            // 16 experts * 8 o-chunks
    int e = b >> 3;
    int oc = (b & 7) * 64;
    int d = t >> 2, seg = (t & 3) * 16;
    const f4* src = (const f4*)(We + ((size_t)(e * DD + d)) * OO + oc + seg);
    f4 v0 = src[0], v1 = src[1], v2 = src[2], v3 = src[3];
#pragma unroll
    for (int j = 0; j < 4; j++) {
      tl[d][seg + j]      = v0[j];
      tl[d][seg + 4 + j]  = v1[j];
      tl[d][seg + 8 + j]  = v2[j];
      tl[d][seg + 12 + j] = v3[j];
    }
    __syncthreads();
    int o = t >> 2, ds = (t & 3) * 16;
    us8 o0, o1;
#pragma unroll
    for (int j = 0; j < 8; j++) {
      o0[j] = f2bf(tl[ds + j][o]);
      o1[j] = f2bf(tl[ds + 8 + j][o]);
    }
    u16* dst = WeT + ((size_t)(e * OO + oc + o)) * DD + ds;
    *(us8*)dst = o0;
    *(us8*)(dst + 8) = o1;
    return;
  }

  // ---- gating: logits -> softmax -> top2; per-block histogram, LDS atomics only ----
  int gb = blockIdx.x - 128;
  hcnt[t] = 0;
  __syncthreads();
  int row = gb * 256 + t;

  float l[NE];
#pragma unroll
  for (int e = 0; e < NE; e++) l[e] = bg[e];

  const f4* xp = (const f4*)(x + (size_t)row * DD);
  for (int d4 = 0; d4 < 16; d4++) {
    f4 xv = xp[d4];
#pragma unroll
    for (int qq = 0; qq < 4; qq++) {
      float xs = xv[qq];
      const float* wrow = wg + (d4 * 4 + qq) * NE;
#pragma unroll
      for (int e = 0; e < NE; e++) l[e] = fmaf(xs, wrow[e], l[e]);
    }
  }
  float mx = l[0];
#pragma unroll
  for (int e = 1; e < NE; e++) mx = fmaxf(mx, l[e]);
  float Z = 0.f;
#pragma unroll
  for (int e = 0; e < NE; e++) Z += __expf(l[e] - mx);
  int i1 = 0; float b1 = l[0];
#pragma unroll
  for (int e = 1; e < NE; e++) { if (l[e] > b1) { b1 = l[e]; i1 = e; } }
  int i2 = -1; float b2 = -1e30f;
#pragma unroll
  for (int e = 0; e < NE; e++) { if (e != i1 && l[e] > b2) { b2 = l[e]; i2 = e; } }
  float p1 = __expf(b1 - mx) / Z;
  float p2 = __expf(b2 - mx) / Z;
  float den = p1 + p2 + 1e-6f;   // reference: top_vals / (sum(top_vals) + 1e-6)
  float g1 = p1 / den, g2 = p2 / den;
  int elo, ehi; float glo, ghi;
  if (i1 < i2) { elo = i1; ehi = i2; glo = g1; ghi = g2; }
  else         { elo = i2; ehi = i1; glo = g2; ghi = g1; }
  u32 pid = (u32)(elo * NE + ehi);
  pid_arr[row] = pid;
  glo_arr[row] = glo;
  ghi_arr[row] = ghi;
  atomicAdd(&hcnt[pid], 1u);   // LDS atomic only
  __syncthreads();
  hist_t[t * 256 + gb] = hcnt[t];   // TRANSPOSED [pid][block]
}

// ---------------- k_meta: colscan + base/tiles + scatter in ONE kernel ----------------
// 256 blocks x 256 thr == 256 CUs -> all blocks co-resident, spin barrier is safe.
// Device-scope atomics + __threadfence per Guideline 16 (cross-XCD L2 non-coherence).
__global__ __launch_bounds__(256)
void k_meta(u32* __restrict__ hist_t, u32* __restrict__ tot, u32* __restrict__ cnt,
            u32* __restrict__ ntp, Tile* __restrict__ tiles,
            const u32* __restrict__ pid_arr, u32* __restrict__ sorted) {
  __shared__ u32 s[256], s2[256], sbase[256], lcnt[256];
  __shared__ u32 lastf;
  int t = threadIdx.x, p = blockIdx.x;

  // ---- phase 1: exclusive scan of own pid row over gate-blocks (coalesced) ----
  u32 v = hist_t[p * 256 + t];
  s[t] = v;
  __syncthreads();
  for (int d = 1; d < 256; d <<= 1) {
    u32 a = 0;
    if (t >= d) a = s[t - d];
    __syncthreads();
    s[t] += a;
    __syncthreads();
  }
  hist_t[p * 256 + t] = s[t] - v;     // in-place exclusive offsets
  if (t == 255) tot[p] = s[255];
  __syncthreads();

  // ---- grid barrier (release -> count -> spin -> acquire) ----
  if (t == 0) {
    __threadfence();                  // release: hist_t/tot visible device-wide
    u32 old = atomicAdd(cnt, 1u);
    lastf = (old == 255u) ? 1u : 0u;
    while (atomicAdd(cnt, 0u) < 256u) __builtin_amdgcn_s_sleep(2);
    __threadfence();                  // acquire: see all other blocks' writes
  }
  __syncthreads();

  // ---- phase 2: redundant per-block prefix over pids; last block builds tiles ----
  u32 tv = tot[t];
  u32 nt = (tv + (TR - 1)) >> 6;
  s[t] = tv; s2[t] = nt;
  __syncthreads();
  for (int d = 1; d < 256; d <<= 1) {
    u32 a = 0, c = 0;
    if (t >= d) { a = s[t - d]; c = s2[t - d]; }
    __syncthreads();
    s[t] += a; s2[t] += c;
    __syncthreads();
  }
  sbase[t] = s[t] - tv;               // row base per pid (kept in LDS for scatter)
  if (lastf) {
    u32 rb = s[t] - tv, tb = s2[t] - nt;
    for (u32 kk = 0; kk < nt; kk++) {
      Tile td;
      td.pid = (u32)t;
      td.slot = rb + kk * (u32)TR;
      u32 rem = tv - kk * (u32)TR;
      td.nr = rem < (u32)TR ? rem : (u32)TR;
      td.pad = 0;
      tiles[tb + kk] = td;
    }
    if (t == 255) *ntp = s2[255];
  }
  __syncthreads();

  // ---- phase 3: scatter this gate-block's rows (block p == gate block p) ----
  lcnt[t] = 0;
  __syncthreads();
  int row = p * 256 + t;
  u32 pid = pid_arr[row];
  u32 rank = atomicAdd(&lcnt[pid], 1u);
  u32 off = sbase[pid] + hist_t[pid * 256 + p];
  sorted[off + rank] = (u32)row;
}

// ---------------- main: per pair-tile GEMM (2 experts) + gated combine ----------------
// UNCHANGED (best measured: R8 197.8us). Swapped-operand MFMA, register combine,
// one barrier, normal cached f4 stores.
__global__ __launch_bounds__(256, 3)
void k_moe(const float* __restrict__ x, const u16* __restrict__ WeT,
           const float* __restrict__ be, const u32* __restrict__ sorted,
           const u32* __restrict__ ntp, const Tile* __restrict__ tiles,
           const float* __restrict__ glo_arr, const float* __restrict__ ghi_arr,
           float* __restrict__ y) {
  __shared__ __align__(16) u16 Xl[TR * 72];     // 9.2 KB, stride 72 breaks conflicts
  __shared__ u32 rid_s[TR];
  __shared__ float glo_s[TR], ghi_s[TR];

  u32 bid = blockIdx.x;
  if (bid >= *ntp) return;
  Tile td = tiles[bid];
  u32 e_lo = td.pid >> 4, e_hi = td.pid & 15u;
  u32 slot0 = td.slot, nr = td.nr;

  int t = threadIdx.x;
  if (t < TR) {
    u32 i = (u32)t;
    u32 slot = slot0 + ((i < nr) ? i : 0u);
    u32 r = sorted[slot];
    rid_s[t] = r;
    bool valid = i < nr;
    glo_s[t] = valid ? glo_arr[r] : 0.f;
    ghi_s[t] = valid ? ghi_arr[r] : 0.f;
  }
  __syncthreads();
  {
    int i = t >> 2;
    int seg = (t & 3) * 16;
    u32 r = rid_s[i];
    const f4* xp = (const f4*)(x + (size_t)r * DD + seg);
    f4 v0 = xp[0], v1 = xp[1], v2 = xp[2], v3 = xp[3];
    float vv[16] = { v0[0], v0[1], v0[2], v0[3], v1[0], v1[1], v1[2], v1[3],
                     v2[0], v2[1], v2[2], v2[3], v3[0], v3[1], v3[2], v3[3] };
    us8 o0, o1;
#pragma unroll
    for (int j = 0; j < 8; j++) { o0[j] = f2bf(vv[j]); o1[j] = f2bf(vv[8 + j]); }
    *(us8*)&Xl[i * 72 + seg] = o0;
    *(us8*)&Xl[i * 72 + seg + 8] = o1;
  }
  __syncthreads();   // the ONLY block-wide barrier

  int lane = t & 63;
  int w = t >> 6;          // wave -> owns 128-col stripe [w*128, w*128+128)
  int q = lane >> 4;       // quad
  int ln = lane & 15;

  // X fragments (B-operand): B[k][n], n = row = rt*16 + ln, k = kc*32 + q*8 + j
  b8 xfr[4][2];
#pragma unroll
  for (int rt = 0; rt < 4; rt++)
#pragma unroll
    for (int kc = 0; kc < 2; kc++) {
      U8 tmp; tmp.u = *(const us8*)&Xl[(rt * 16 + ln) * 72 + kc * 32 + q * 8];
      xfr[rt][kc] = tmp.b;
    }

  // per-lane gate + output-row metadata: one row per rt (row = rt*16 + ln)
  float gl[4], gh[4];
  bool vld[4];
  float* yp[4];
#pragma unroll
  for (int rt = 0; rt < 4; rt++) {
    int i = rt * 16 + ln;
    gl[rt] = glo_s[i];
    gh[rt] = ghi_s[i];
    vld[rt] = (u32)i < nr;
    yp[rt] = y + (size_t)rid_s[i] * OO;
  }

  const u16* wlo = WeT + (size_t)e_lo * OO * DD;
  const u16* whi = WeT + (size_t)e_hi * OO * DD;
  const f4 zero = {0.f, 0.f, 0.f, 0.f};

  // 8 col-tiles of 16 per wave; no barriers, stores fire-and-forget
#pragma unroll 2
  for (int ct = 0; ct < 8; ct++) {
    int colA = w * 128 + ct * 16 + ln;       // A-fragment col (lane-indexed)
    int colq = w * 128 + ct * 16 + q * 4;    // this lane's contiguous col quad
    const us8* plo = (const us8*)(wlo + (size_t)colA * DD + q * 8);
    const us8* phi = (const us8*)(whi + (size_t)colA * DD + q * 8);
    U8 t0, t1, t2, t3;
    t0.u = plo[0]; t1.u = plo[4];   // +32 elems = k-chunk 1
    t2.u = phi[0]; t3.u = phi[4];
    b8 wl0 = t0.b, wl1 = t1.b, wh0 = t2.b, wh1 = t3.b;
    f4 bl = *(const f4*)(be + e_lo * OO + colq);
    f4 bh = *(const f4*)(be + e_hi * OO + colq);

#pragma unroll
    for (int rt = 0; rt < 4; rt++) {
      f4 aL = zero, aH = zero;
      aL = __builtin_amdgcn_mfma_f32_16x16x32_bf16(wl0, xfr[rt][0], aL, 0, 0, 0);
      aL = __builtin_amdgcn_mfma_f32_16x16x32_bf16(wl1, xfr[rt][1], aL, 0, 0, 0);
      aH = __builtin_amdgcn_mfma_f32_16x16x32_bf16(wh0, xfr[rt][0], aH, 0, 0, 0);
      aH = __builtin_amdgcn_mfma_f32_16x16x32_bf16(wh1, xfr[rt][1], aH, 0, 0, 0);
      if (vld[rt]) {
        f4 v;
#pragma unroll
        for (int r = 0; r < 4; r++)
          v[r] = gl[rt] * (aL[r] + bl[r]) + gh[rt] * (aH[r] + bh[r]);
        *(f4*)(yp[rt] + colq) = v;   // normal cached store (L2 write-combines)
      }
    }
  }
}

extern "C" void kernel_launch(void* const* d_in, const int* in_sizes, int n_in,
                              void* d_out, int out_size, void* d_ws, size_t ws_size,
                              hipStream_t stream) {
  const float* x  = (const float*)d_in[0];
  const float* wg = (const float*)d_in[1];
  const float* bg = (const float*)d_in[2];
  const float* We = (const float*)d_in[3];
  const float* be = (const float*)d_in[4];
  float* y = (float*)d_out;

  char* ws = (char*)d_ws;
  u32* ntp     = (u32*)(ws + 0);                       // 1 u32
  u32* cnt     = (u32*)(ws + 64);                      // barrier counter (reset by k_front)
  Tile* tiles  = (Tile*)(ws + 4096);                   // <= 1792 * 16B
  u32* pid_arr = (u32*)(ws + 32768);                   // 65536 u32
  float* glo_a = (float*)(ws + 32768 + 262144);        // 65536 f32
  float* ghi_a = (float*)(ws + 32768 + 2 * 262144);    // 65536 f32
  u32* sorted  = (u32*)(ws + 32768 + 3 * 262144);      // 65536 u32
  u16* WeT     = (u16*)(ws + 32768 + 4 * 262144);      // 524288 bf16 (1MB)
  u32* hist_t  = (u32*)(ws + 32768 + 4 * 262144 + 1048576);            // 256*256 u32 [pid][block]
  u32* tot     = (u32*)(ws + 32768 + 4 * 262144 + 1048576 + 262144);   // 256 u32

  k_front<<<384, 256, 0, stream>>>(We, WeT, x, wg, bg, hist_t, pid_arr, glo_a, ghi_a, cnt);
  k_meta<<<256, 256, 0, stream>>>(hist_t, tot, cnt, ntp, tiles, pid_arr, sorted);
  k_moe<<<1144, 256, 0, stream>>>(x, WeT, be, sorted, ntp, tiles, glo_a, ghi_a, y);
}

// Round 11
// 195.500 us; speedup vs baseline: 1.0582x; 1.0582x over previous
//
#include <hip/hip_runtime.h>

typedef unsigned int u32;
typedef unsigned short u16;
typedef float f4 __attribute__((ext_vector_type(4)));
typedef __bf16 b8 __attribute__((ext_vector_type(8)));
typedef unsigned short us8 __attribute__((ext_vector_type(8)));

#define DD 64
#define NE 16
#define OO 512
#define TR 64

struct __align__(16) Tile { u32 pid, slot, nr, pad; };

union U8 { us8 u; b8 b; };

__device__ __forceinline__ u16 f2bf(float f) {
  u32 u = __float_as_uint(f);
  u32 r = (u + 0x7fffu + ((u >> 16) & 1u)) >> 16;
  return (u16)r;
}

// ---------------- fused front: blocks [0,128) transpose We; blocks [128,384) gate ----------------
__global__ void k_front(const float* __restrict__ We, u16* __restrict__ WeT,
                        const float* __restrict__ x, const float* __restrict__ wg,
                        const float* __restrict__ bg, u32* __restrict__ hist_t,
                        u32* __restrict__ pid_arr, float* __restrict__ glo_arr,
                        float* __restrict__ ghi_arr) {
  __shared__ float tl[64][65];     // wt path (16.6 KB)
  __shared__ u32 hcnt[256];        // gate path (1 KB)
  int t = threadIdx.x;

  if (blockIdx.x < 128) {
    // ---- We [e][d][o] fp32 -> WeT [e][o][d] bf16 ----
    int b = blockIdx.x;            // 16 experts * 8 o-chunks
    int e = b >> 3;
    int oc = (b & 7) * 64;
    int d = t >> 2, seg = (t & 3) * 16;
    const f4* src = (const f4*)(We + ((size_t)(e * DD + d)) * OO + oc + seg);
    f4 v0 = src[0], v1 = src[1], v2 = src[2], v3 = src[3];
#pragma unroll
    for (int j = 0; j < 4; j++) {
      tl[d][seg + j]      = v0[j];
      tl[d][seg + 4 + j]  = v1[j];
      tl[d][seg + 8 + j]  = v2[j];
      tl[d][seg + 12 + j] = v3[j];
    }
    __syncthreads();
    int o = t >> 2, ds = (t & 3) * 16;
    us8 o0, o1;
#pragma unroll
    for (int j = 0; j < 8; j++) {
      o0[j] = f2bf(tl[ds + j][o]);
      o1[j] = f2bf(tl[ds + 8 + j][o]);
    }
    u16* dst = WeT + ((size_t)(e * OO + oc + o)) * DD + ds;
    *(us8*)dst = o0;
    *(us8*)(dst + 8) = o1;
    return;
  }

  // ---- gating: logits -> softmax -> top2; per-block histogram, LDS atomics only ----
  int gb = blockIdx.x - 128;
  hcnt[t] = 0;
  __syncthreads();
  int row = gb * 256 + t;

  float l[NE];
#pragma unroll
  for (int e = 0; e < NE; e++) l[e] = bg[e];

  const f4* xp = (const f4*)(x + (size_t)row * DD);
  for (int d4 = 0; d4 < 16; d4++) {
    f4 xv = xp[d4];
#pragma unroll
    for (int qq = 0; qq < 4; qq++) {
      float xs = xv[qq];
      const float* wrow = wg + (d4 * 4 + qq) * NE;
#pragma unroll
      for (int e = 0; e < NE; e++) l[e] = fmaf(xs, wrow[e], l[e]);
    }
  }
  float mx = l[0];
#pragma unroll
  for (int e = 1; e < NE; e++) mx = fmaxf(mx, l[e]);
  float Z = 0.f;
#pragma unroll
  for (int e = 0; e < NE; e++) Z += __expf(l[e] - mx);
  int i1 = 0; float b1 = l[0];
#pragma unroll
  for (int e = 1; e < NE; e++) { if (l[e] > b1) { b1 = l[e]; i1 = e; } }
  int i2 = -1; float b2 = -1e30f;
#pragma unroll
  for (int e = 0; e < NE; e++) { if (e != i1 && l[e] > b2) { b2 = l[e]; i2 = e; } }
  float p1 = __expf(b1 - mx) / Z;
  float p2 = __expf(b2 - mx) / Z;
  float den = p1 + p2 + 1e-6f;   // reference: top_vals / (sum(top_vals) + 1e-6)
  float g1 = p1 / den, g2 = p2 / den;
  int elo, ehi; float glo, ghi;
  if (i1 < i2) { elo = i1; ehi = i2; glo = g1; ghi = g2; }
  else         { elo = i2; ehi = i1; glo = g2; ghi = g1; }
  u32 pid = (u32)(elo * NE + ehi);
  pid_arr[row] = pid;
  glo_arr[row] = glo;
  ghi_arr[row] = ghi;
  atomicAdd(&hcnt[pid], 1u);   // LDS atomic only
  __syncthreads();
  hist_t[t * 256 + gb] = hcnt[t];   // TRANSPOSED [pid][block]
}

// ---------------- per-pid scan over gate-blocks (COALESCED on hist_t) ----------------
// 256 blocks (one per pid), full machine parallelism (R7's 1-block k_mid cost +9us).
__global__ void k_colscan_t(u32* __restrict__ hist_t, u32* __restrict__ tot) {
  __shared__ u32 s[256];
  int b = threadIdx.x, p = blockIdx.x;
  u32 v = hist_t[p * 256 + b];   // coalesced
  s[b] = v;
  __syncthreads();
  for (int d = 1; d < 256; d <<= 1) {
    u32 a = 0;
    if (b >= d) a = s[b - d];
    __syncthreads();
    s[b] += a;
    __syncthreads();
  }
  hist_t[p * 256 + b] = s[b] - v;   // in-place local exclusive offset
  if (b == 255) tot[p] = s[255];
}

// ---------------- scatter + absorbed k_base (one fewer launch than R8) ----------------
// All 256 blocks redundantly prefix-scan tot[] in LDS (~1us, parallel) instead of
// reading a precomputed base[]; block 0 additionally builds tiles/ntp (consumed only
// by k_moe -> kernel-boundary ordering, NO grid barrier needed; R9's spin cost +9us).
__global__ void k_scatter2(const u32* __restrict__ pid_arr, const u32* __restrict__ hist_t,
                           const u32* __restrict__ tot, u32* __restrict__ ntp,
                           Tile* __restrict__ tiles, u32* __restrict__ sorted) {
  __shared__ u32 s[256], s2[256], sbase[256], lcnt[256];
  int t = threadIdx.x, b = blockIdx.x;
  u32 v = tot[t];
  u32 nt = (v + (TR - 1)) >> 6;
  s[t] = v; s2[t] = nt;
  __syncthreads();
  for (int d = 1; d < 256; d <<= 1) {
    u32 a = 0, c = 0;
    if (t >= d) { a = s[t - d]; c = s2[t - d]; }
    __syncthreads();
    s[t] += a; s2[t] += c;
    __syncthreads();
  }
  sbase[t] = s[t] - v;
  lcnt[t] = 0;
  if (b == 0) {
    u32 rb = s[t] - v, tb = s2[t] - nt;
    for (u32 kk = 0; kk < nt; kk++) {
      Tile td;
      td.pid = (u32)t;
      td.slot = rb + kk * (u32)TR;
      u32 rem = v - kk * (u32)TR;
      td.nr = rem < (u32)TR ? rem : (u32)TR;
      td.pad = 0;
      tiles[tb + kk] = td;
    }
    if (t == 255) *ntp = s2[255];
  }
  __syncthreads();
  int row = b * 256 + t;
  u32 pid = pid_arr[row];
  u32 rank = atomicAdd(&lcnt[pid], 1u);
  u32 off = sbase[pid] + hist_t[pid * 256 + b];
  sorted[off + rank] = (u32)row;
}

// ---------------- main: per pair-tile GEMM (2 experts) + gated combine ----------------
// UNCHANGED (best measured: R8 197.8us). Swapped-operand MFMA, register combine,
// one barrier, normal cached f4 stores (nt regressed +7.3us).
__global__ __launch_bounds__(256, 3)
void k_moe(const float* __restrict__ x, const u16* __restrict__ WeT,
           const float* __restrict__ be, const u32* __restrict__ sorted,
           const u32* __restrict__ ntp, const Tile* __restrict__ tiles,
           const float* __restrict__ glo_arr, const float* __restrict__ ghi_arr,
           float* __restrict__ y) {
  __shared__ __align__(16) u16 Xl[TR * 72];     // 9.2 KB, stride 72 breaks conflicts
  __shared__ u32 rid_s[TR];
  __shared__ float glo_s[TR], ghi_s[TR];

  u32 bid = blockIdx.x;
  if (bid >= *ntp) return;
  Tile td = tiles[bid];
  u32 e_lo = td.pid >> 4, e_hi = td.pid & 15u;
  u32 slot0 = td.slot, nr = td.nr;

  int t = threadIdx.x;
  if (t < TR) {
    u32 i = (u32)t;
    u32 slot = slot0 + ((i < nr) ? i : 0u);
    u32 r = sorted[slot];
    rid_s[t] = r;
    bool valid = i < nr;
    glo_s[t] = valid ? glo_arr[r] : 0.f;
    ghi_s[t] = valid ? ghi_arr[r] : 0.f;
  }
  __syncthreads();
  {
    int i = t >> 2;
    int seg = (t & 3) * 16;
    u32 r = rid_s[i];
    const f4* xp = (const f4*)(x + (size_t)r * DD + seg);
    f4 v0 = xp[0], v1 = xp[1], v2 = xp[2], v3 = xp[3];
    float vv[16] = { v0[0], v0[1], v0[2], v0[3], v1[0], v1[1], v1[2], v1[3],
                     v2[0], v2[1], v2[2], v2[3], v3[0], v3[1], v3[2], v3[3] };
    us8 o0, o1;
#pragma unroll
    for (int j = 0; j < 8; j++) { o0[j] = f2bf(vv[j]); o1[j] = f2bf(vv[8 + j]); }
    *(us8*)&Xl[i * 72 + seg] = o0;
    *(us8*)&Xl[i * 72 + seg + 8] = o1;
  }
  __syncthreads();   // the ONLY block-wide barrier

  int lane = t & 63;
  int w = t >> 6;          // wave -> owns 128-col stripe [w*128, w*128+128)
  int q = lane >> 4;       // quad
  int ln = lane & 15;

  // X fragments (B-operand): B[k][n], n = row = rt*16 + ln, k = kc*32 + q*8 + j
  b8 xfr[4][2];
#pragma unroll
  for (int rt = 0; rt < 4; rt++)
#pragma unroll
    for (int kc = 0; kc < 2; kc++) {
      U8 tmp; tmp.u = *(const us8*)&Xl[(rt * 16 + ln) * 72 + kc * 32 + q * 8];
      xfr[rt][kc] = tmp.b;
    }

  // per-lane gate + output-row metadata: one row per rt (row = rt*16 + ln)
  float gl[4], gh[4];
  bool vld[4];
  float* yp[4];
#pragma unroll
  for (int rt = 0; rt < 4; rt++) {
    int i = rt * 16 + ln;
    gl[rt] = glo_s[i];
    gh[rt] = ghi_s[i];
    vld[rt] = (u32)i < nr;
    yp[rt] = y + (size_t)rid_s[i] * OO;
  }

  const u16* wlo = WeT + (size_t)e_lo * OO * DD;
  const u16* whi = WeT + (size_t)e_hi * OO * DD;
  const f4 zero = {0.f, 0.f, 0.f, 0.f};

  // 8 col-tiles of 16 per wave; no barriers, stores fire-and-forget
#pragma unroll 2
  for (int ct = 0; ct < 8; ct++) {
    int colA = w * 128 + ct * 16 + ln;       // A-fragment col (lane-indexed)
    int colq = w * 128 + ct * 16 + q * 4;    // this lane's contiguous col quad
    const us8* plo = (const us8*)(wlo + (size_t)colA * DD + q * 8);
    const us8* phi = (const us8*)(whi + (size_t)colA * DD + q * 8);
    U8 t0, t1, t2, t3;
    t0.u = plo[0]; t1.u = plo[4];   // +32 elems = k-chunk 1
    t2.u = phi[0]; t3.u = phi[4];
    b8 wl0 = t0.b, wl1 = t1.b, wh0 = t2.b, wh1 = t3.b;
    f4 bl = *(const f4*)(be + e_lo * OO + colq);
    f4 bh = *(const f4*)(be + e_hi * OO + colq);

#pragma unroll
    for (int rt = 0; rt < 4; rt++) {
      f4 aL = zero, aH = zero;
      aL = __builtin_amdgcn_mfma_f32_16x16x32_bf16(wl0, xfr[rt][0], aL, 0, 0, 0);
      aL = __builtin_amdgcn_mfma_f32_16x16x32_bf16(wl1, xfr[rt][1], aL, 0, 0, 0);
      aH = __builtin_amdgcn_mfma_f32_16x16x32_bf16(wh0, xfr[rt][0], aH, 0, 0, 0);
      aH = __builtin_amdgcn_mfma_f32_16x16x32_bf16(wh1, xfr[rt][1], aH, 0, 0, 0);
      if (vld[rt]) {
        f4 v;
#pragma unroll
        for (int r = 0; r < 4; r++)
          v[r] = gl[rt] * (aL[r] + bl[r]) + gh[rt] * (aH[r] + bh[r]);
        *(f4*)(yp[rt] + colq) = v;   // normal cached store (L2 write-combines)
      }
    }
  }
}

extern "C" void kernel_launch(void* const* d_in, const int* in_sizes, int n_in,
                              void* d_out, int out_size, void* d_ws, size_t ws_size,
                              hipStream_t stream) {
  const float* x  = (const float*)d_in[0];
  const float* wg = (const float*)d_in[1];
  const float* bg = (const float*)d_in[2];
  const float* We = (const float*)d_in[3];
  const float* be = (const float*)d_in[4];
  float* y = (float*)d_out;

  char* ws = (char*)d_ws;
  u32* ntp     = (u32*)(ws + 0);                       // 1 u32
  Tile* tiles  = (Tile*)(ws + 4096);                   // <= 1344 * 16B
  u32* pid_arr = (u32*)(ws + 32768);                   // 65536 u32
  float* glo_a = (float*)(ws + 32768 + 262144);        // 65536 f32
  float* ghi_a = (float*)(ws + 32768 + 2 * 262144);    // 65536 f32
  u32* sorted  = (u32*)(ws + 32768 + 3 * 262144);      // 65536 u32
  u16* WeT     = (u16*)(ws + 32768 + 4 * 262144);      // 524288 bf16 (1MB)
  u32* hist_t  = (u32*)(ws + 32768 + 4 * 262144 + 1048576);            // 256*256 u32 [pid][block]
  u32* tot     = (u32*)(ws + 32768 + 4 * 262144 + 1048576 + 262144);   // 256 u32

  k_front<<<384, 256, 0, stream>>>(We, WeT, x, wg, bg, hist_t, pid_arr, glo_a, ghi_a);
  k_colscan_t<<<256, 256, 0, stream>>>(hist_t, tot);
  k_scatter2<<<256, 256, 0, stream>>>(pid_arr, hist_t, tot, ntp, tiles, sorted);
  k_moe<<<1144, 256, 0, stream>>>(x, WeT, be, sorted, ntp, tiles, glo_a, ghi_a, y);
}